// Round 13
// baseline (438.181 us; speedup 1.0000x reference)
//
#include <hip/hip_runtime.h>
#include <hip/hip_bf16.h>
#include <math.h>

#define N_NODES 50000
#define N_EDGES 1600000
#define IN_C 165
#define HID 256
#define HEADS 8
#define C1 32
#define OUT_C 2
#define NEG_SLOPE 0.2f
#define LOG2E 1.44269504088896f
#define TROWS 32                           // gemm tile rows (mfma 32x32)
#define GEMM_BLOCKS ((N_NODES + TROWS - 1) / TROWS)  // 1563
#define SCB 2048                           // scatter blocks (8 classes x 256)
#define SGRP 256                           // scatter blocks per class
#define NPP ((N_NODES + 7) / 8)            // 6250 nodes per dst partition
#define CAPL 96                            // fixed per-node list capacity
#define NE4 (N_EDGES / 4)                  // 400000 int4-scan elements

// ---- MFMA gemm geometry (R7, unchanged) ----
#define NSTEP 11
#define BIMG_BYTES ((size_t)NSTEP * 16384)                 // 176 KB
#define WAIMG_BYTES ((size_t)NSTEP * 2048)                 // 22.5 KB
#define WT (NSTEP * 512)
#define WPB ((WT + 255) / 256)             // 22
#define WAT (176 * 16)
#define WAB ((WAT + 255) / 256)            // 11

typedef float f32x2 __attribute__((ext_vector_type(2)));
typedef short s16x8 __attribute__((ext_vector_type(8)));
typedef float f32x16 __attribute__((ext_vector_type(16)));

__device__ inline float lrelu(float v) { return v > 0.f ? v : NEG_SLOPE * v; }
// weight from PRE-SCALED (x log2e) logit: exp(lrelu(x)) = exp2(lrelu(x*log2e))
__device__ inline float e2l(float t) { return exp2f(fmaxf(t, NEG_SLOPE * t)); }

// fp32 -> bf16 bits, round-to-nearest-even
__device__ inline unsigned short f32_bf16(float f) {
    unsigned u = __float_as_uint(f);
    return (unsigned short)((u + 0x7FFFu + ((u >> 16) & 1u)) >> 16);
}

__device__ inline float bflo(unsigned u) { return __uint_as_float(u << 16); }
__device__ inline float bfhi(unsigned u) { return __uint_as_float(u & 0xFFFF0000u); }
__device__ inline float bf2f(unsigned short b) { return __uint_as_float(((unsigned)b) << 16); }

// ============ prepass: W fragment image + Wa (= W*att) fragment image =======
__global__ __launch_bounds__(256) void prep_kernel(
        const float* __restrict__ W,
        const float* __restrict__ att_src, const float* __restrict__ att_dst,
        unsigned short* __restrict__ bImg, unsigned short* __restrict__ waImg) {
    if (blockIdx.x < WPB) {
        int g2 = blockIdx.x * 256 + threadIdx.x;
        if (g2 >= WT) return;
        int s = g2 >> 9;
        int r9 = g2 & 511;
        int kg = r9 >> 8, nsub = (r9 >> 5) & 7, c32 = r9 & 31;
        int col = nsub * 32 + c32;
        int k0 = s * 16 + kg * 8;
        unsigned short hb[8], lb[8];
        #pragma unroll
        for (int i = 0; i < 8; ++i) {
            int k = k0 + i;
            float v = (k < IN_C) ? W[(size_t)k * HID + col] : 0.f;
            hb[i] = f32_bf16(v);
            lb[i] = f32_bf16(v - bf2f(hb[i]));
        }
        unsigned ph[4], pl[4];
        #pragma unroll
        for (int q = 0; q < 4; ++q) {
            ph[q] = (unsigned)hb[2*q] | ((unsigned)hb[2*q+1] << 16);
            pl[q] = (unsigned)lb[2*q] | ((unsigned)lb[2*q+1] << 16);
        }
        unsigned short* base = bImg + (size_t)s * 8192
                             + ((nsub * 2 + kg) * 32 + c32) * 8;
        *(uint4*)(base)        = make_uint4(ph[0], ph[1], ph[2], ph[3]);
        *(uint4*)(base + 4096) = make_uint4(pl[0], pl[1], pl[2], pl[3]);
    } else {
        int g2 = (blockIdx.x - WPB) * 256 + threadIdx.x;
        if (g2 >= WAT) return;
        int k = g2 >> 4, j = g2 & 15;
        int head = j >> 1;
        float dotv = 0.f;
        if (k < IN_C) {
            const float* wr = W + (size_t)k * HID + head * 32;
            const float* at = ((j & 1) ? att_dst : att_src) + head * 32;
            #pragma unroll
            for (int c = 0; c < 32; c += 4) {
                float4 wv = *(const float4*)(wr + c);
                float4 av = *(const float4*)(at + c);
                dotv += wv.x*av.x + wv.y*av.y + wv.z*av.z + wv.w*av.w;
            }
        }
        unsigned short dh = f32_bf16(dotv);
        unsigned short dl = f32_bf16(dotv - bf2f(dh));
        int s = k >> 4, kk = k & 15, kg = kk >> 3, i = kk & 7;
        unsigned short* base = waImg + (size_t)s * 1024 + (kg * 32 + j) * 8 + i;
        base[0]   = dh;     // split h
        base[512] = dl;     // split l
    }
}

// ============ MFMA gemm1 + fused attention-dot tiles (R11 head-major) =======
__device__ __forceinline__ void gemm_mfma_block(
        int b, const float* __restrict__ x,
        const unsigned short* __restrict__ bImg,
        const unsigned short* __restrict__ waImg,
        unsigned short* __restrict__ h1h, float* __restrict__ a_srcH,
        float* __restrict__ a_dstH, unsigned short* asr) {
    const int tid = threadIdx.x;
    const int w = tid >> 6, l = tid & 63;
    const int half = l >> 5, ln = l & 31;
    const int row0 = b * TROWS;
    for (int g = tid; g < 704; g += 256) {
        int o = g >> 5, row = g & 31;
        int s = o >> 1, kg = o & 1;
        int node = row0 + row;
        int k0 = o * 8;
        unsigned short hb[8], lb[8];
        #pragma unroll
        for (int i = 0; i < 8; ++i) {
            int k = k0 + i;
            float v = (node < N_NODES && k < IN_C) ? x[(size_t)node * IN_C + k] : 0.f;
            hb[i] = f32_bf16(v);
            lb[i] = f32_bf16(v - bf2f(hb[i]));
        }
        unsigned ph[4], pl[4];
        #pragma unroll
        for (int q = 0; q < 4; ++q) {
            ph[q] = (unsigned)hb[2*q] | ((unsigned)hb[2*q+1] << 16);
            pl[q] = (unsigned)lb[2*q] | ((unsigned)lb[2*q+1] << 16);
        }
        unsigned short* base = asr + s * 1024 + (kg * 32 + row) * 8;
        *(uint4*)(base)       = make_uint4(ph[0], ph[1], ph[2], ph[3]);
        *(uint4*)(base + 512) = make_uint4(pl[0], pl[1], pl[2], pl[3]);
    }
    __syncthreads();

    f32x16 acc0, acc1, accA;
    #pragma unroll
    for (int r = 0; r < 16; ++r) { acc0[r] = 0.f; acc1[r] = 0.f; accA[r] = 0.f; }
    const int ns0 = 2 * w, ns1 = 2 * w + 1;
    const int afo = (half * 32 + ln) * 8;     // A/Wa frag offset (shorts)
    const int fo0 = ((ns0 * 2 + half) * 32 + ln) * 8;
    const int fo1 = ((ns1 * 2 + half) * 32 + ln) * 8;
    for (int s = 0; s < NSTEP; ++s) {
        const unsigned short* ab = asr + s * 1024;
        s16x8 a_h = *(const s16x8*)(ab + afo);
        s16x8 a_l = *(const s16x8*)(ab + 512 + afo);
        const unsigned short* bb = bImg + (size_t)s * 8192;
        s16x8 bh0 = *(const s16x8*)(bb + fo0);
        s16x8 bh1 = *(const s16x8*)(bb + fo1);
        s16x8 bl0 = *(const s16x8*)(bb + 4096 + fo0);
        s16x8 bl1 = *(const s16x8*)(bb + 4096 + fo1);
        acc0 = __builtin_amdgcn_mfma_f32_32x32x16_bf16(a_h, bh0, acc0, 0, 0, 0);
        acc1 = __builtin_amdgcn_mfma_f32_32x32x16_bf16(a_h, bh1, acc1, 0, 0, 0);
        acc0 = __builtin_amdgcn_mfma_f32_32x32x16_bf16(a_h, bl0, acc0, 0, 0, 0);
        acc1 = __builtin_amdgcn_mfma_f32_32x32x16_bf16(a_h, bl1, acc1, 0, 0, 0);
        acc0 = __builtin_amdgcn_mfma_f32_32x32x16_bf16(a_l, bh0, acc0, 0, 0, 0);
        acc1 = __builtin_amdgcn_mfma_f32_32x32x16_bf16(a_l, bh1, acc1, 0, 0, 0);
        if (w == 0) {                          // wave-uniform branch
            const unsigned short* wb = waImg + (size_t)s * 1024;
            s16x8 wah = *(const s16x8*)(wb + afo);
            s16x8 wal = *(const s16x8*)(wb + 512 + afo);
            accA = __builtin_amdgcn_mfma_f32_32x32x16_bf16(a_h, wah, accA, 0, 0, 0);
            accA = __builtin_amdgcn_mfma_f32_32x32x16_bf16(a_h, wal, accA, 0, 0, 0);
            accA = __builtin_amdgcn_mfma_f32_32x32x16_bf16(a_l, wah, accA, 0, 0, 0);
        }
    }
    // ---- epilogue: h stores (head-major, 64B row per (node,head)) ----
    #pragma unroll
    for (int t = 0; t < 2; ++t) {
        const int head = w * 2 + t;
        #pragma unroll
        for (int r = 0; r < 16; ++r) {
            int row = (r & 3) + 8 * (r >> 2) + 4 * half;
            int gr = row0 + row;
            if (gr < N_NODES) {
                float a = t ? acc1[r] : acc0[r];
                h1h[((size_t)head * N_NODES + gr) * 32 + ln] = f32_bf16(a);
            }
        }
    }
    // ---- epilogue: attention logits (head-major) ----
    if (w == 0 && ln < 16) {
        int head = ln >> 1;
        float* ap = (ln & 1) ? a_dstH : a_srcH;
        #pragma unroll
        for (int r = 0; r < 16; ++r) {
            int row = (r & 3) + 8 * (r >> 2) + 4 * half;
            int gr = row0 + row;
            if (gr < N_NODES) ap[(size_t)head * N_NODES + gr] = accA[r] * LOG2E;
        }
    }
}

// ============ fused: MFMA gemm || partition-filtered slotted scatter ========
__global__ __launch_bounds__(256) void fusedAB_kernel(
        const float* __restrict__ x,
        const unsigned short* __restrict__ bImg,
        const unsigned short* __restrict__ waImg,
        unsigned short* __restrict__ h1h, float* __restrict__ a_srcH,
        float* __restrict__ a_dstH,
        const int* __restrict__ src, const int* __restrict__ dst,
        int* __restrict__ deg, unsigned short* __restrict__ csr) {
    __shared__ unsigned short asr[NSTEP * 1024];   // 22.5 KB A-fragment region
    if (blockIdx.x < GEMM_BLOCKS) {
        gemm_mfma_block(blockIdx.x, x, bImg, waImg, h1h, a_srcH, a_dstH, asr);
    } else {
        const int sb  = blockIdx.x - GEMM_BLOCKS;   // 0..SCB-1
        const int cls = sb & 7;
        const int blk = sb >> 3;                    // 0..255 within class
        const int lo = cls * NPP;
        const int hi = (lo + NPP < N_NODES) ? lo + NPP : N_NODES;
        const int t = blk * 256 + threadIdx.x;      // 0..65535 within class
        const int4* dst4 = (const int4*)dst;        // int4 scan of real edges
        for (int uu = t; uu < NE4; uu += SGRP * 256) {
            int4 dv = dst4[uu];
            #pragma unroll
            for (int j = 0; j < 4; ++j) {
                int d = (j == 0) ? dv.x : (j == 1) ? dv.y : (j == 2) ? dv.z : dv.w;
                if (d >= lo && d < hi) {
                    int slot = atomicAdd(&deg[d], 1);
                    csr[(size_t)d * CAPL + slot] = (unsigned short)src[4 * uu + j];
                }
            }
        }
    }
}

// ============ Layer 1 aggregate, HEAD-SPLIT v3 (R13) ============
// R12 lesson: locality held (FETCH 74MB) but 4-nodes-per-wave divergence
// (+20% masked waste) and 8-edge rounds made it VALU-bound at 146us.
// R13: wave = ONE (node, head) -> zero divergence; lane = es(0..15) x
// c4(0..3); 16 edges/round in flight (R10-par MLP); uint4 gathers.
// Block = 512 thr = 8 nodes x one head; head = blockIdx&7 -> XCD-local
// 3.2MB h1h slice; grid = 6250 x 8 = 50000 blocks.
__global__ __launch_bounds__(512) void agg1h_kernel(
        const int* __restrict__ deg, const unsigned short* __restrict__ csr,
        const float* __restrict__ a_srcH, const float* __restrict__ a_dstH,
        const unsigned short* __restrict__ h1h, const float* __restrict__ bias1,
        const float* __restrict__ W2, float* __restrict__ partial) {
    const int h = blockIdx.x & 7;
    const int node = (blockIdx.x >> 3) * 8 + (threadIdx.x >> 6);  // 6250*8=50000
    const int l = threadIdx.x & 63;
    const int es = l >> 2;                    // edge slot 0..15
    const int c4 = l & 3;                     // channel quad 0..3 (8 ch each)
    const unsigned short* lst = csr + (size_t)node * CAPL;
    const int n = deg[node];
    const float* asrc = a_srcH + (size_t)h * N_NODES;
    const float ad_p = a_dstH[(size_t)h * N_NODES + node];
    const unsigned short* hs = h1h + (size_t)h * N_NODES * 32;
    float den = 0.f;
    float ac[8];
    #pragma unroll
    for (int k = 0; k < 8; ++k) ac[k] = 0.f;
    int i = 0;
    for (; i + 16 <= n; i += 16) {            // 16 edges/round in flight
        int s = lst[i + es];
        uint4 v = *(const uint4*)(hs + (size_t)s * 32 + c4 * 8);
        float w = e2l(asrc[s] + ad_p);
        den += w;
        ac[0] += w * bflo(v.x); ac[1] += w * bfhi(v.x);
        ac[2] += w * bflo(v.y); ac[3] += w * bfhi(v.y);
        ac[4] += w * bflo(v.z); ac[5] += w * bfhi(v.z);
        ac[6] += w * bflo(v.w); ac[7] += w * bfhi(v.w);
    }
    if (i < n) {                              // masked tail (up to 16 edges)
        int e = i + es;
        bool ok = e < n;
        int s = ok ? lst[e] : node;           // clamp to own row (L2-local)
        uint4 v = *(const uint4*)(hs + (size_t)s * 32 + c4 * 8);
        float w = (ok ? 1.f : 0.f) * e2l(asrc[s] + ad_p);
        den += w;
        ac[0] += w * bflo(v.x); ac[1] += w * bfhi(v.x);
        ac[2] += w * bflo(v.y); ac[3] += w * bfhi(v.y);
        ac[4] += w * bflo(v.z); ac[5] += w * bfhi(v.z);
        ac[6] += w * bflo(v.w); ac[7] += w * bfhi(v.w);
    }
    // reduce over the 16 edge slots (lane bits 2..5); c4 (bits 0..1) intact
    #pragma unroll
    for (int off = 4; off <= 32; off <<= 1) {
        den += __shfl_xor(den, off);
        #pragma unroll
        for (int k = 0; k < 8; ++k) ac[k] += __shfl_xor(ac[k], off);
    }
    // self-loop term (each lane adds its own c4 slice once; den consistent)
    {
        uint4 v = *(const uint4*)(hs + (size_t)node * 32 + c4 * 8);
        float ws = e2l(asrc[node] + ad_p);
        den += ws;
        ac[0] += ws * bflo(v.x); ac[1] += ws * bfhi(v.x);
        ac[2] += ws * bflo(v.y); ac[3] += ws * bfhi(v.y);
        ac[4] += ws * bflo(v.z); ac[5] += ws * bfhi(v.z);
        ac[6] += ws * bflo(v.w); ac[7] += ws * bfhi(v.w);
    }
    const float inv = 1.f / den;
    float4 bva = *(const float4*)(bias1 + h * 32 + c4 * 8);
    float4 bvb = *(const float4*)(bias1 + h * 32 + c4 * 8 + 4);
    float o[8];
    o[0] = ac[0] * inv + bva.x; o[1] = ac[1] * inv + bva.y;
    o[2] = ac[2] * inv + bva.z; o[3] = ac[3] * inv + bva.w;
    o[4] = ac[4] * inv + bvb.x; o[5] = ac[5] * inv + bvb.y;
    o[6] = ac[6] * inv + bvb.z; o[7] = ac[7] * inv + bvb.w;
    #pragma unroll
    for (int k = 0; k < 8; ++k)               // ELU (exp-1 err ~1e-7 << tol)
        o[k] = o[k] > 0.f ? o[k] : (__expf(o[k]) - 1.f);
    // W2 partial: rows h*32 + c4*8 .. +7, 2 cols, row-major
    const float* wv = W2 + (h * 32 + c4 * 8) * 2;
    float4 w0 = *(const float4*)(wv);
    float4 w1 = *(const float4*)(wv + 4);
    float4 w2 = *(const float4*)(wv + 8);
    float4 w3 = *(const float4*)(wv + 12);
    float p0 = o[0]*w0.x + o[1]*w0.z + o[2]*w1.x + o[3]*w1.z
             + o[4]*w2.x + o[5]*w2.z + o[6]*w3.x + o[7]*w3.z;
    float p1 = o[0]*w0.y + o[1]*w0.w + o[2]*w1.y + o[3]*w1.w
             + o[4]*w2.y + o[5]*w2.w + o[6]*w3.y + o[7]*w3.w;
    p0 += __shfl_xor(p0, 1); p0 += __shfl_xor(p0, 2);   // reduce over c4
    p1 += __shfl_xor(p1, 1); p1 += __shfl_xor(p1, 2);
    if (l == 0)
        *(float2*)(partial + (size_t)node * 16 + h * 2) = make_float2(p0, p1);
}

// ============ finalize: sum head partials -> pk, a2d ============
__global__ __launch_bounds__(256) void fin_kernel(
        const float* __restrict__ partial,
        const float* __restrict__ as2, const float* __restrict__ ad2,
        float4* __restrict__ pk, float* __restrict__ a2d) {
    int node = blockIdx.x * 256 + threadIdx.x;
    if (node >= N_NODES) return;
    const float4* pp = (const float4*)(partial + (size_t)node * 16);
    float4 q0 = pp[0], q1 = pp[1], q2 = pp[2], q3 = pp[3];
    float p0 = q0.x + q0.z + q1.x + q1.z + q2.x + q2.z + q3.x + q3.z;
    float p1 = q0.y + q0.w + q1.y + q1.w + q2.y + q2.w + q3.y + q3.w;
    pk[node] = make_float4(p0, p1, (p0 * as2[0] + p1 * as2[1]) * LOG2E, 0.f);
    a2d[node] = (p0 * ad2[0] + p1 * ad2[1]) * LOG2E;
}

// ============ Layer 2 fused (unchanged R10) ============
__global__ __launch_bounds__(256) void agg2_fused_kernel(
        const int* __restrict__ deg, const unsigned short* __restrict__ csr,
        const float4* __restrict__ pk, const float* __restrict__ a2d,
        const float* __restrict__ b2, float* __restrict__ out) {
    int t = blockIdx.x * 256 + threadIdx.x;
    int node = t >> 4;
    int l = t & 15;
    if (node >= N_NODES) return;
    const unsigned short* lst = csr + (size_t)node * CAPL;
    const int n = deg[node];
    const float adv = a2d[node];
    float sm = 0.f, acc0 = 0.f, acc1 = 0.f;
    for (int i = l; i < n; i += 32) {
        int s0 = lst[i];
        int e1 = i + 16;
        bool ok1 = e1 < n;
        float m1 = ok1 ? 1.f : 0.f;
        int s1 = ok1 ? lst[e1] : node;
        float4 p0 = pk[s0], p1 = pk[s1];
        float w0 = e2l(p0.z + adv);
        float w1 = m1 * e2l(p1.z + adv);
        sm += w0 + w1;
        acc0 += w0 * p0.x + w1 * p1.x;
        acc1 += w0 * p0.y + w1 * p1.y;
    }
    #pragma unroll
    for (int off = 8; off; off >>= 1) {       // xor stays within the 16-group
        sm   += __shfl_xor(sm, off);
        acc0 += __shfl_xor(acc0, off);
        acc1 += __shfl_xor(acc1, off);
    }
    if (l == 0) {
        float4 ps = pk[node];                 // explicit self-loop term
        float wsf = e2l(ps.z + adv);
        sm += wsf;
        acc0 += wsf * ps.x;
        acc1 += wsf * ps.y;
        *(float2*)(out + node * 2) =
            make_float2(acc0 / sm + b2[0], acc1 / sm + b2[1]);
    }
}

extern "C" void kernel_launch(void* const* d_in, const int* in_sizes, int n_in,
                              void* d_out, int out_size, void* d_ws, size_t ws_size,
                              hipStream_t stream) {
    (void)in_sizes; (void)n_in; (void)out_size; (void)ws_size;
    const float* x        = (const float*)d_in[0];
    const int*   ei       = (const int*)d_in[1];
    const float* W1       = (const float*)d_in[2];
    const float* att_src1 = (const float*)d_in[3];
    const float* att_dst1 = (const float*)d_in[4];
    const float* b1       = (const float*)d_in[5];
    const float* W2       = (const float*)d_in[6];
    const float* att_src2 = (const float*)d_in[7];
    const float* att_dst2 = (const float*)d_in[8];
    const float* b2       = (const float*)d_in[9];
    float* out = (float*)d_out;

    const int* src = ei;
    const int* dst = ei + N_EDGES;

    // ---- workspace carve-up (bytes); total ~43 MB ----
    char* ws = (char*)d_ws;
    size_t off = 0;
    unsigned short* h1h = (unsigned short*)(ws + off);
    off += (size_t)N_NODES * HID * 2;                                      // 25.6 MB
    float* a_srcH = (float*)(ws + off); off += (size_t)N_NODES * HEADS * 4;
    float* a_dstH = (float*)(ws + off); off += (size_t)N_NODES * HEADS * 4;
    float4* pk = (float4*)(ws + off); off += (size_t)N_NODES * 16;
    float* a2d = (float*)(ws + off); off += (size_t)N_NODES * 4;
    int* deg    = (int*)(ws + off); off += (size_t)N_NODES * 4;
    unsigned short* csr = (unsigned short*)(ws + off);
    off += (size_t)N_NODES * CAPL * 2;                                     // 9.6 MB
    float* partial = (float*)(ws + off); off += (size_t)N_NODES * 16 * 4;  // 3.2 MB
    unsigned short* bImg  = (unsigned short*)(ws + off); off += BIMG_BYTES;  // 176 KB
    unsigned short* waImg = (unsigned short*)(ws + off); off += WAIMG_BYTES; // 22.5 KB

    hipMemsetAsync(deg, 0, (size_t)N_NODES * 4, stream);

    // ---- prepass: W and Wa fragment-major split-bf16 images ----
    prep_kernel<<<WPB + WAB, 256, 0, stream>>>(W1, att_src1, att_dst1, bImg, waImg);

    // ---- MFMA gemm + att dots || scatter (no self-loops) ----
    fusedAB_kernel<<<GEMM_BLOCKS + SCB, 256, 0, stream>>>(
        x, bImg, waImg, h1h, a_srcH, a_dstH, src, dst, deg, csr);

    // ---- layer 1 aggregate, head-split v3 (1 wave per node-head) ----
    agg1h_kernel<<<(N_NODES / 8) * 8, 512, 0, stream>>>(
        deg, csr, a_srcH, a_dstH, h1h, b1, W2, partial);

    // ---- finalize: sum head partials -> pk/a2d ----
    fin_kernel<<<(N_NODES + 255) / 256, 256, 0, stream>>>(
        partial, att_src2, att_dst2, pk, a2d);

    // ---- layer 2 aggregate ----
    agg2_fused_kernel<<<(N_NODES * 16 + 255) / 256, 256, 0, stream>>>(
        deg, csr, pk, a2d, b2, out);
}

// Round 14
// 319.947 us; speedup vs baseline: 1.3695x; 1.3695x over previous
//
#include <hip/hip_runtime.h>
#include <hip/hip_bf16.h>
#include <math.h>

#define N_NODES 50000
#define N_EDGES 1600000
#define IN_C 165
#define HID 256
#define HEADS 8
#define C1 32
#define OUT_C 2
#define NEG_SLOPE 0.2f
#define LOG2E 1.44269504088896f
#define TROWS 32                           // gemm tile rows (mfma 32x32)
#define GEMM_BLOCKS ((N_NODES + TROWS - 1) / TROWS)  // 1563
#define SCB 2048                           // scatter blocks (8 classes x 256)
#define SGRP 256                           // scatter blocks per class
#define NPP ((N_NODES + 7) / 8)            // 6250 nodes per dst partition
#define CAPL 96                            // fixed per-node list capacity
#define NE4 (N_EDGES / 4)                  // 400000 int4-scan elements

// ---- MFMA gemm geometry (R7, unchanged) ----
#define NSTEP 11
#define BIMG_BYTES ((size_t)NSTEP * 16384)                 // 176 KB
#define WAIMG_BYTES ((size_t)NSTEP * 2048)                 // 22.5 KB
#define WT (NSTEP * 512)
#define WPB ((WT + 255) / 256)             // 22
#define WAT (176 * 16)
#define WAB ((WAT + 255) / 256)            // 11

typedef float f32x2 __attribute__((ext_vector_type(2)));
typedef short s16x8 __attribute__((ext_vector_type(8)));
typedef float f32x16 __attribute__((ext_vector_type(16)));

__device__ inline float lrelu(float v) { return v > 0.f ? v : NEG_SLOPE * v; }
// weight from PRE-SCALED (x log2e) logit: exp(lrelu(x)) = exp2(lrelu(x*log2e))
__device__ inline float e2l(float t) { return exp2f(fmaxf(t, NEG_SLOPE * t)); }

// fp32 -> bf16 bits, round-to-nearest-even
__device__ inline unsigned short f32_bf16(float f) {
    unsigned u = __float_as_uint(f);
    return (unsigned short)((u + 0x7FFFu + ((u >> 16) & 1u)) >> 16);
}

__device__ inline float bflo(unsigned u) { return __uint_as_float(u << 16); }
__device__ inline float bfhi(unsigned u) { return __uint_as_float(u & 0xFFFF0000u); }
__device__ inline float bf2f(unsigned short b) { return __uint_as_float(((unsigned)b) << 16); }

// ============ prepass: W fragment image + Wa (= W*att) fragment image =======
__global__ __launch_bounds__(256) void prep_kernel(
        const float* __restrict__ W,
        const float* __restrict__ att_src, const float* __restrict__ att_dst,
        unsigned short* __restrict__ bImg, unsigned short* __restrict__ waImg) {
    if (blockIdx.x < WPB) {
        int g2 = blockIdx.x * 256 + threadIdx.x;
        if (g2 >= WT) return;
        int s = g2 >> 9;
        int r9 = g2 & 511;
        int kg = r9 >> 8, nsub = (r9 >> 5) & 7, c32 = r9 & 31;
        int col = nsub * 32 + c32;
        int k0 = s * 16 + kg * 8;
        unsigned short hb[8], lb[8];
        #pragma unroll
        for (int i = 0; i < 8; ++i) {
            int k = k0 + i;
            float v = (k < IN_C) ? W[(size_t)k * HID + col] : 0.f;
            hb[i] = f32_bf16(v);
            lb[i] = f32_bf16(v - bf2f(hb[i]));
        }
        unsigned ph[4], pl[4];
        #pragma unroll
        for (int q = 0; q < 4; ++q) {
            ph[q] = (unsigned)hb[2*q] | ((unsigned)hb[2*q+1] << 16);
            pl[q] = (unsigned)lb[2*q] | ((unsigned)lb[2*q+1] << 16);
        }
        unsigned short* base = bImg + (size_t)s * 8192
                             + ((nsub * 2 + kg) * 32 + c32) * 8;
        *(uint4*)(base)        = make_uint4(ph[0], ph[1], ph[2], ph[3]);
        *(uint4*)(base + 4096) = make_uint4(pl[0], pl[1], pl[2], pl[3]);
    } else {
        int g2 = (blockIdx.x - WPB) * 256 + threadIdx.x;
        if (g2 >= WAT) return;
        int k = g2 >> 4, j = g2 & 15;
        int head = j >> 1;
        float dotv = 0.f;
        if (k < IN_C) {
            const float* wr = W + (size_t)k * HID + head * 32;
            const float* at = ((j & 1) ? att_dst : att_src) + head * 32;
            #pragma unroll
            for (int c = 0; c < 32; c += 4) {
                float4 wv = *(const float4*)(wr + c);
                float4 av = *(const float4*)(at + c);
                dotv += wv.x*av.x + wv.y*av.y + wv.z*av.z + wv.w*av.w;
            }
        }
        unsigned short dh = f32_bf16(dotv);
        unsigned short dl = f32_bf16(dotv - bf2f(dh));
        int s = k >> 4, kk = k & 15, kg = kk >> 3, i = kk & 7;
        unsigned short* base = waImg + (size_t)s * 1024 + (kg * 32 + j) * 8 + i;
        base[0]   = dh;     // split h
        base[512] = dl;     // split l
    }
}

// ============ MFMA gemm1 + fused attention-dot tiles (R7/R10) ============
__device__ __forceinline__ void gemm_mfma_block(
        int b, const float* __restrict__ x,
        const unsigned short* __restrict__ bImg,
        const unsigned short* __restrict__ waImg,
        unsigned short* __restrict__ h, float* __restrict__ a_src,
        float* __restrict__ a_dst, unsigned short* asr) {
    const int tid = threadIdx.x;
    const int w = tid >> 6, l = tid & 63;
    const int half = l >> 5, ln = l & 31;
    const int row0 = b * TROWS;
    for (int g = tid; g < 704; g += 256) {
        int o = g >> 5, row = g & 31;
        int s = o >> 1, kg = o & 1;
        int node = row0 + row;
        int k0 = o * 8;
        unsigned short hb[8], lb[8];
        #pragma unroll
        for (int i = 0; i < 8; ++i) {
            int k = k0 + i;
            float v = (node < N_NODES && k < IN_C) ? x[(size_t)node * IN_C + k] : 0.f;
            hb[i] = f32_bf16(v);
            lb[i] = f32_bf16(v - bf2f(hb[i]));
        }
        unsigned ph[4], pl[4];
        #pragma unroll
        for (int q = 0; q < 4; ++q) {
            ph[q] = (unsigned)hb[2*q] | ((unsigned)hb[2*q+1] << 16);
            pl[q] = (unsigned)lb[2*q] | ((unsigned)lb[2*q+1] << 16);
        }
        unsigned short* base = asr + s * 1024 + (kg * 32 + row) * 8;
        *(uint4*)(base)       = make_uint4(ph[0], ph[1], ph[2], ph[3]);
        *(uint4*)(base + 512) = make_uint4(pl[0], pl[1], pl[2], pl[3]);
    }
    __syncthreads();

    f32x16 acc0, acc1, accA;
    #pragma unroll
    for (int r = 0; r < 16; ++r) { acc0[r] = 0.f; acc1[r] = 0.f; accA[r] = 0.f; }
    const int ns0 = 2 * w, ns1 = 2 * w + 1;
    const int afo = (half * 32 + ln) * 8;     // A/Wa frag offset (shorts)
    const int fo0 = ((ns0 * 2 + half) * 32 + ln) * 8;
    const int fo1 = ((ns1 * 2 + half) * 32 + ln) * 8;
    for (int s = 0; s < NSTEP; ++s) {
        const unsigned short* ab = asr + s * 1024;
        s16x8 a_h = *(const s16x8*)(ab + afo);
        s16x8 a_l = *(const s16x8*)(ab + 512 + afo);
        const unsigned short* bb = bImg + (size_t)s * 8192;
        s16x8 bh0 = *(const s16x8*)(bb + fo0);
        s16x8 bh1 = *(const s16x8*)(bb + fo1);
        s16x8 bl0 = *(const s16x8*)(bb + 4096 + fo0);
        s16x8 bl1 = *(const s16x8*)(bb + 4096 + fo1);
        acc0 = __builtin_amdgcn_mfma_f32_32x32x16_bf16(a_h, bh0, acc0, 0, 0, 0);
        acc1 = __builtin_amdgcn_mfma_f32_32x32x16_bf16(a_h, bh1, acc1, 0, 0, 0);
        acc0 = __builtin_amdgcn_mfma_f32_32x32x16_bf16(a_h, bl0, acc0, 0, 0, 0);
        acc1 = __builtin_amdgcn_mfma_f32_32x32x16_bf16(a_h, bl1, acc1, 0, 0, 0);
        acc0 = __builtin_amdgcn_mfma_f32_32x32x16_bf16(a_l, bh0, acc0, 0, 0, 0);
        acc1 = __builtin_amdgcn_mfma_f32_32x32x16_bf16(a_l, bh1, acc1, 0, 0, 0);
        if (w == 0) {                          // wave-uniform branch
            const unsigned short* wb = waImg + (size_t)s * 1024;
            s16x8 wah = *(const s16x8*)(wb + afo);
            s16x8 wal = *(const s16x8*)(wb + 512 + afo);
            accA = __builtin_amdgcn_mfma_f32_32x32x16_bf16(a_h, wah, accA, 0, 0, 0);
            accA = __builtin_amdgcn_mfma_f32_32x32x16_bf16(a_h, wal, accA, 0, 0, 0);
            accA = __builtin_amdgcn_mfma_f32_32x32x16_bf16(a_l, wah, accA, 0, 0, 0);
        }
    }
    #pragma unroll
    for (int t = 0; t < 2; ++t) {
        const int colg = w * 64 + t * 32 + ln;
        #pragma unroll
        for (int r = 0; r < 16; ++r) {
            int row = (r & 3) + 8 * (r >> 2) + 4 * half;
            int gr = row0 + row;
            if (gr < N_NODES) {
                float a = t ? acc1[r] : acc0[r];
                h[(size_t)gr * HID + colg] = f32_bf16(a);
            }
        }
    }
    if (w == 0 && ln < 16) {
        int head = ln >> 1;
        float* ap = (ln & 1) ? a_dst : a_src;
        #pragma unroll
        for (int r = 0; r < 16; ++r) {
            int row = (r & 3) + 8 * (r >> 2) + 4 * half;
            int gr = row0 + row;
            if (gr < N_NODES) ap[gr * 8 + head] = accA[r] * LOG2E;
        }
    }
}

// ============ fused: MFMA gemm || partition-filtered slotted scatter ========
// Self-loops NOT inserted (added analytically in agg1/agg2).
__global__ __launch_bounds__(256) void fusedAB_kernel(
        const float* __restrict__ x,
        const unsigned short* __restrict__ bImg,
        const unsigned short* __restrict__ waImg,
        unsigned short* __restrict__ h, float* __restrict__ a_src,
        float* __restrict__ a_dst,
        const int* __restrict__ src, const int* __restrict__ dst,
        int* __restrict__ deg, unsigned short* __restrict__ csr) {
    __shared__ unsigned short asr[NSTEP * 1024];   // 22.5 KB A-fragment region
    if (blockIdx.x < GEMM_BLOCKS) {
        gemm_mfma_block(blockIdx.x, x, bImg, waImg, h, a_src, a_dst, asr);
    } else {
        const int sb  = blockIdx.x - GEMM_BLOCKS;   // 0..SCB-1
        const int cls = sb & 7;
        const int blk = sb >> 3;                    // 0..255 within class
        const int lo = cls * NPP;
        const int hi = (lo + NPP < N_NODES) ? lo + NPP : N_NODES;
        const int t = blk * 256 + threadIdx.x;      // 0..65535 within class
        const int4* dst4 = (const int4*)dst;        // int4 scan of real edges
        for (int uu = t; uu < NE4; uu += SGRP * 256) {
            int4 dv = dst4[uu];
            #pragma unroll
            for (int j = 0; j < 4; ++j) {
                int d = (j == 0) ? dv.x : (j == 1) ? dv.y : (j == 2) ? dv.z : dv.w;
                if (d >= lo && d < hi) {
                    int slot = atomicAdd(&deg[d], 1);
                    csr[(size_t)d * CAPL + slot] = (unsigned short)src[4 * uu + j];
                }
            }
        }
    }
}

// ============ Layer 1 fused: softmax-aggregate(bf16 gather) + bias + ELU
//              + layer-2 GEMM.  Register-resident edge list, 32-edge rounds,
//              analytic self-loop. (R10 — pinned at the 422MB/3.6TB/s IC
//              floor; three instruction-structure variants all ~118-122us,
//              three head-split locality variants all worse. FLOOR.) ========
__global__ __launch_bounds__(256) void agg1_fused_kernel(
        const int* __restrict__ deg, const unsigned short* __restrict__ csr,
        const float* __restrict__ a_src, const float* __restrict__ a_dst,
        const unsigned short* __restrict__ h1, const float* __restrict__ bias1,
        const float* __restrict__ W2,
        const float* __restrict__ as2, const float* __restrict__ ad2,
        float4* __restrict__ pk, float* __restrict__ a2d) {
    int wid = (blockIdx.x * 256 + threadIdx.x) >> 6;
    int l = threadIdx.x & 63;
    if (wid >= N_NODES) return;
    const int el = l >> 5;                    // edge parity (half-wave)
    const int q  = l & 31;                    // channel octet id
    const int hd = q >> 2;                    // head
    const int ch = q * 8;                     // ushort offset (16 B per lane)
    const int sh = el * 16;                   // halfword select shift
    const uint4* lst4 = (const uint4*)(csr + (size_t)wid * CAPL);
    const int n = deg[wid];
    const float ad_p = a_dst[wid * 8 + hd];
    float den = 0.f;
    f32x2 ac0 = {0.f, 0.f}, ac1 = {0.f, 0.f}, ac2 = {0.f, 0.f}, ac3 = {0.f, 0.f};

    uint4 ca = lst4[0], cb = lst4[1], cc = lst4[2], cd = lst4[3];
    int i = 0;

#define EXTRACT_S(S_, MK_, OFF_, W0_, W1_, W2_, W3_, W4_, W5_, W6_, W7_)      \
    {                                                                          \
        unsigned wsel_[8] = {W0_, W1_, W2_, W3_, W4_, W5_, W6_, W7_};          \
        _Pragma("unroll")                                                      \
        for (int j = 0; j < 8; ++j) {                                          \
            int sv = (int)((wsel_[j] >> sh) & 0xFFFFu);                        \
            int e = i + OFF_ + 2 * j + el;                                     \
            bool ok = e < n;                                                   \
            MK_[j] = ok ? 1.f : 0.f;                                           \
            S_[j] = ok ? sv : wid;                                             \
        }                                                                      \
    }

#define GATHER_ACC(S_, MK_, CNT_)                                              \
    {                                                                          \
        uint4 v_[CNT_];                                                        \
        _Pragma("unroll")                                                      \
        for (int j = 0; j < CNT_; ++j)                                         \
            v_[j] = *(const uint4*)(h1 + (size_t)S_[j] * HID + ch);            \
        float w_[CNT_];                                                        \
        _Pragma("unroll")                                                      \
        for (int j = 0; j < CNT_; ++j)                                         \
            w_[j] = MK_[j] * e2l(a_src[S_[j] * 8 + hd] + ad_p);                \
        _Pragma("unroll")                                                      \
        for (int j = 0; j < CNT_; ++j) {                                       \
            den += w_[j];                                                      \
            f32x2 w2_ = {w_[j], w_[j]};                                        \
            ac0 += w2_ * (f32x2){bflo(v_[j].x), bfhi(v_[j].x)};                \
            ac1 += w2_ * (f32x2){bflo(v_[j].y), bfhi(v_[j].y)};                \
            ac2 += w2_ * (f32x2){bflo(v_[j].z), bfhi(v_[j].z)};                \
            ac3 += w2_ * (f32x2){bflo(v_[j].w), bfhi(v_[j].w)};                \
        }                                                                      \
    }

    for (; i + 32 <= n; i += 32) {
        uint4 na = ca, nb = cb, nc = cc, nd = cd;
        if (i + 32 < n) {
            na = lst4[(i >> 3) + 4]; nb = lst4[(i >> 3) + 5];
            nc = lst4[(i >> 3) + 6]; nd = lst4[(i >> 3) + 7];
        }
        int s[16]; float mk[16];
        EXTRACT_S(s, mk, 0,  ca.x, ca.y, ca.z, ca.w, cb.x, cb.y, cb.z, cb.w)
        EXTRACT_S((s + 8), (mk + 8), 16, cc.x, cc.y, cc.z, cc.w, cd.x, cd.y, cd.z, cd.w)
        GATHER_ACC(s, mk, 16)
        ca = na; cb = nb; cc = nc; cd = nd;
    }
    if (i + 16 <= n) {
        int s[8]; float mk[8];
        EXTRACT_S(s, mk, 0, ca.x, ca.y, ca.z, ca.w, cb.x, cb.y, cb.z, cb.w)
        GATHER_ACC(s, mk, 8)
        ca = cc; cb = cd;
        i += 16;
    }
    if (i < n) {
        int s[8]; float mk[8];
        EXTRACT_S(s, mk, 0, ca.x, ca.y, ca.z, ca.w, cb.x, cb.y, cb.z, cb.w)
        GATHER_ACC(s, mk, 8)
    }
#undef EXTRACT_S
#undef GATHER_ACC

    float accs[8] = {ac0.x, ac0.y, ac1.x, ac1.y, ac2.x, ac2.y, ac3.x, ac3.y};
    den += __shfl_xor(den, 32);
    #pragma unroll
    for (int k = 0; k < 8; ++k) accs[k] += __shfl_xor(accs[k], 32);

    // ---- explicit self-loop term (not in csr) ----
    {
        float wsf = e2l(a_src[wid * 8 + hd] + ad_p);
        uint4 v = *(const uint4*)(h1 + (size_t)wid * HID + ch);
        den += wsf;
        accs[0] += wsf * bflo(v.x); accs[1] += wsf * bfhi(v.x);
        accs[2] += wsf * bflo(v.y); accs[3] += wsf * bfhi(v.y);
        accs[4] += wsf * bflo(v.z); accs[5] += wsf * bfhi(v.z);
        accs[6] += wsf * bflo(v.w); accs[7] += wsf * bfhi(v.w);
    }

    const float inv = 1.f / den;
    float4 bva = *(const float4*)(bias1 + ch);
    float4 bvb = *(const float4*)(bias1 + ch + 4);
    float o[8];
    o[0] = accs[0] * inv + bva.x; o[1] = accs[1] * inv + bva.y;
    o[2] = accs[2] * inv + bva.z; o[3] = accs[3] * inv + bva.w;
    o[4] = accs[4] * inv + bvb.x; o[5] = accs[5] * inv + bvb.y;
    o[6] = accs[6] * inv + bvb.z; o[7] = accs[7] * inv + bvb.w;
    #pragma unroll
    for (int k = 0; k < 8; ++k)               // ELU; exp-1 abs err ~1e-7 << tol
        o[k] = o[k] > 0.f ? o[k] : (__expf(o[k]) - 1.f);
    const float* wv = W2 + q * 16;
    float4 w0 = *(const float4*)(wv);
    float4 w1 = *(const float4*)(wv + 4);
    float4 w2 = *(const float4*)(wv + 8);
    float4 w3 = *(const float4*)(wv + 12);
    float p0 = o[0]*w0.x + o[1]*w0.z + o[2]*w1.x + o[3]*w1.z
             + o[4]*w2.x + o[5]*w2.z + o[6]*w3.x + o[7]*w3.z;
    float p1 = o[0]*w0.y + o[1]*w0.w + o[2]*w1.y + o[3]*w1.w
             + o[4]*w2.y + o[5]*w2.w + o[6]*w3.y + o[7]*w3.w;
    #pragma unroll
    for (int off = 16; off; off >>= 1) {
        p0 += __shfl_xor(p0, off);
        p1 += __shfl_xor(p1, off);
    }
    if (l == 0) {
        pk[wid] = make_float4(p0, p1, (p0 * as2[0] + p1 * as2[1]) * LOG2E, 0.f);
        a2d[wid] = (p0 * ad2[0] + p1 * ad2[1]) * LOG2E;
    }
}

// ============ Layer 2 fused: 16 lanes per node, 2-deep rounds.
// Masked slots clamp to `node` (uniform, cache-hit). Self term at l==0. ====
__global__ __launch_bounds__(256) void agg2_fused_kernel(
        const int* __restrict__ deg, const unsigned short* __restrict__ csr,
        const float4* __restrict__ pk, const float* __restrict__ a2d,
        const float* __restrict__ b2, float* __restrict__ out) {
    int t = blockIdx.x * 256 + threadIdx.x;
    int node = t >> 4;
    int l = t & 15;
    if (node >= N_NODES) return;
    const unsigned short* lst = csr + (size_t)node * CAPL;
    const int n = deg[node];
    const float adv = a2d[node];
    float sm = 0.f, acc0 = 0.f, acc1 = 0.f;
    for (int i = l; i < n; i += 32) {
        int s0 = lst[i];
        int e1 = i + 16;
        bool ok1 = e1 < n;
        float m1 = ok1 ? 1.f : 0.f;
        int s1 = ok1 ? lst[e1] : node;
        float4 p0 = pk[s0], p1 = pk[s1];
        float w0 = e2l(p0.z + adv);
        float w1 = m1 * e2l(p1.z + adv);
        sm += w0 + w1;
        acc0 += w0 * p0.x + w1 * p1.x;
        acc1 += w0 * p0.y + w1 * p1.y;
    }
    #pragma unroll
    for (int off = 8; off; off >>= 1) {       // xor stays within the 16-group
        sm   += __shfl_xor(sm, off);
        acc0 += __shfl_xor(acc0, off);
        acc1 += __shfl_xor(acc1, off);
    }
    if (l == 0) {
        float4 ps = pk[node];                 // explicit self-loop term
        float wsf = e2l(ps.z + adv);
        sm += wsf;
        acc0 += wsf * ps.x;
        acc1 += wsf * ps.y;
        *(float2*)(out + node * 2) =
            make_float2(acc0 / sm + b2[0], acc1 / sm + b2[1]);
    }
}

extern "C" void kernel_launch(void* const* d_in, const int* in_sizes, int n_in,
                              void* d_out, int out_size, void* d_ws, size_t ws_size,
                              hipStream_t stream) {
    (void)in_sizes; (void)n_in; (void)out_size; (void)ws_size;
    const float* x        = (const float*)d_in[0];
    const int*   ei       = (const int*)d_in[1];
    const float* W1       = (const float*)d_in[2];
    const float* att_src1 = (const float*)d_in[3];
    const float* att_dst1 = (const float*)d_in[4];
    const float* b1       = (const float*)d_in[5];
    const float* W2       = (const float*)d_in[6];
    const float* att_src2 = (const float*)d_in[7];
    const float* att_dst2 = (const float*)d_in[8];
    const float* b2       = (const float*)d_in[9];
    float* out = (float*)d_out;

    const int* src = ei;
    const int* dst = ei + N_EDGES;

    // ---- workspace carve-up (bytes); total ~39.8 MB ----
    char* ws = (char*)d_ws;
    size_t off = 0;
    unsigned short* h1 = (unsigned short*)(ws + off);
    off += (size_t)N_NODES * HID * 2;                                      // 25.6 MB
    float* a_src1 = (float*)(ws + off); off += (size_t)N_NODES * HEADS * 4;
    float* a_dst1 = (float*)(ws + off); off += (size_t)N_NODES * HEADS * 4;
    float4* pk = (float4*)(ws + off); off += (size_t)N_NODES * 16;
    float* a2d = (float*)(ws + off); off += (size_t)N_NODES * 4;
    int* deg    = (int*)(ws + off); off += (size_t)N_NODES * 4;
    unsigned short* csr = (unsigned short*)(ws + off);
    off += (size_t)N_NODES * CAPL * 2;                                     // 9.6 MB
    unsigned short* bImg  = (unsigned short*)(ws + off); off += BIMG_BYTES;  // 176 KB
    unsigned short* waImg = (unsigned short*)(ws + off); off += WAIMG_BYTES; // 22.5 KB

    hipMemsetAsync(deg, 0, (size_t)N_NODES * 4, stream);

    const int NW = (N_NODES * 64 + 255) / 256;

    // ---- prepass: W and Wa fragment-major split-bf16 images ----
    prep_kernel<<<WPB + WAB, 256, 0, stream>>>(W1, att_src1, att_dst1, bImg, waImg);

    // ---- MFMA gemm + att dots || scatter (no self-loops) ----
    fusedAB_kernel<<<GEMM_BLOCKS + SCB, 256, 0, stream>>>(
        x, bImg, waImg, h1, a_src1, a_dst1, src, dst, deg, csr);

    // ---- layer 1 aggregate + ELU + layer 2 GEMM (fused) ----
    agg1_fused_kernel<<<NW, 256, 0, stream>>>(
        deg, csr, a_src1, a_dst1, h1, b1, W2, att_src2, att_dst2, pk, a2d);

    // ---- layer 2 aggregate ----
    agg2_fused_kernel<<<(N_NODES * 16 + 255) / 256, 256, 0, stream>>>(
        deg, csr, pk, a2d, b2, out);
}

// Round 15
// 315.000 us; speedup vs baseline: 1.3911x; 1.0157x over previous
//
#include <hip/hip_runtime.h>
#include <hip/hip_bf16.h>
#include <math.h>

#define N_NODES 50000
#define N_EDGES 1600000
#define IN_C 165
#define HID 256
#define HEADS 8
#define C1 32
#define OUT_C 2
#define NEG_SLOPE 0.2f
#define LOG2E 1.44269504088896f
#define TROWS 32                           // gemm tile rows (mfma 32x32)
#define GEMM_BLOCKS ((N_NODES + TROWS - 1) / TROWS)  // 1563
#define SCB 2048                           // scatter blocks (8 classes x 256)
#define SGRP 256                           // scatter blocks per class
#define NPP ((N_NODES + 7) / 8)            // 6250 nodes per dst partition
#define CAPL 96                            // fixed per-node list capacity
#define NE4 (N_EDGES / 4)                  // 400000 int4-scan elements

// ---- MFMA gemm geometry (R7, unchanged) ----
#define NSTEP 11
#define BIMG_BYTES ((size_t)NSTEP * 16384)                 // 176 KB
#define WAIMG_BYTES ((size_t)NSTEP * 2048)                 // 22.5 KB
#define WT (NSTEP * 512)
#define WPB ((WT + 255) / 256)             // 22
#define WAT (176 * 16)
#define WAB ((WAT + 255) / 256)            // 11

typedef float f32x2 __attribute__((ext_vector_type(2)));
typedef short s16x8 __attribute__((ext_vector_type(8)));
typedef float f32x16 __attribute__((ext_vector_type(16)));

__device__ inline float lrelu(float v) { return v > 0.f ? v : NEG_SLOPE * v; }
// weight from PRE-SCALED (x log2e) logit: exp(lrelu(x)) = exp2(lrelu(x*log2e))
__device__ inline float e2l(float t) { return exp2f(fmaxf(t, NEG_SLOPE * t)); }

// fp32 -> bf16 bits, round-to-nearest-even
__device__ inline unsigned short f32_bf16(float f) {
    unsigned u = __float_as_uint(f);
    return (unsigned short)((u + 0x7FFFu + ((u >> 16) & 1u)) >> 16);
}

__device__ inline float bflo(unsigned u) { return __uint_as_float(u << 16); }
__device__ inline float bfhi(unsigned u) { return __uint_as_float(u & 0xFFFF0000u); }
__device__ inline float bf2f(unsigned short b) { return __uint_as_float(((unsigned)b) << 16); }

// ============ prepass: W fragment image + Wa (= W*att) fragment image =======
__global__ __launch_bounds__(256) void prep_kernel(
        const float* __restrict__ W,
        const float* __restrict__ att_src, const float* __restrict__ att_dst,
        unsigned short* __restrict__ bImg, unsigned short* __restrict__ waImg) {
    if (blockIdx.x < WPB) {
        int g2 = blockIdx.x * 256 + threadIdx.x;
        if (g2 >= WT) return;
        int s = g2 >> 9;
        int r9 = g2 & 511;
        int kg = r9 >> 8, nsub = (r9 >> 5) & 7, c32 = r9 & 31;
        int col = nsub * 32 + c32;
        int k0 = s * 16 + kg * 8;
        unsigned short hb[8], lb[8];
        #pragma unroll
        for (int i = 0; i < 8; ++i) {
            int k = k0 + i;
            float v = (k < IN_C) ? W[(size_t)k * HID + col] : 0.f;
            hb[i] = f32_bf16(v);
            lb[i] = f32_bf16(v - bf2f(hb[i]));
        }
        unsigned ph[4], pl[4];
        #pragma unroll
        for (int q = 0; q < 4; ++q) {
            ph[q] = (unsigned)hb[2*q] | ((unsigned)hb[2*q+1] << 16);
            pl[q] = (unsigned)lb[2*q] | ((unsigned)lb[2*q+1] << 16);
        }
        unsigned short* base = bImg + (size_t)s * 8192
                             + ((nsub * 2 + kg) * 32 + c32) * 8;
        *(uint4*)(base)        = make_uint4(ph[0], ph[1], ph[2], ph[3]);
        *(uint4*)(base + 4096) = make_uint4(pl[0], pl[1], pl[2], pl[3]);
    } else {
        int g2 = (blockIdx.x - WPB) * 256 + threadIdx.x;
        if (g2 >= WAT) return;
        int k = g2 >> 4, j = g2 & 15;
        int head = j >> 1;
        float dotv = 0.f;
        if (k < IN_C) {
            const float* wr = W + (size_t)k * HID + head * 32;
            const float* at = ((j & 1) ? att_dst : att_src) + head * 32;
            #pragma unroll
            for (int c = 0; c < 32; c += 4) {
                float4 wv = *(const float4*)(wr + c);
                float4 av = *(const float4*)(at + c);
                dotv += wv.x*av.x + wv.y*av.y + wv.z*av.z + wv.w*av.w;
            }
        }
        unsigned short dh = f32_bf16(dotv);
        unsigned short dl = f32_bf16(dotv - bf2f(dh));
        int s = k >> 4, kk = k & 15, kg = kk >> 3, i = kk & 7;
        unsigned short* base = waImg + (size_t)s * 1024 + (kg * 32 + j) * 8 + i;
        base[0]   = dh;     // split h
        base[512] = dl;     // split l
    }
}

// ============ MFMA gemm1 + fused attention-dot tiles ============
// R15: prologue conversion vectorized (2x16B memcpy loads, per-granule
// bounds specialization) + TRUNC split with pair-packing (~4 ops/elem vs
// ~10). Trunc residual <= 2^-14|x| -> h error ~1e-4, 40x below the bf16
// h-storage rounding that sets absmax. h-epilogue keeps RNE.
__device__ __forceinline__ void gemm_mfma_block(
        int b, const float* __restrict__ x,
        const unsigned short* __restrict__ bImg,
        const unsigned short* __restrict__ waImg,
        unsigned short* __restrict__ h, float* __restrict__ a_src,
        float* __restrict__ a_dst, unsigned short* asr) {
    const int tid = threadIdx.x;
    const int w = tid >> 6, l = tid & 63;
    const int half = l >> 5, ln = l & 31;
    const int row0 = b * TROWS;
    for (int g = tid; g < 704; g += 256) {
        int o = g >> 5, row = g & 31;
        int s = o >> 1, kg = o & 1;
        int node = row0 + row;
        float va0=0.f, va1=0.f, va2=0.f, va3=0.f;
        float vb0=0.f, vb1=0.f, vb2=0.f, vb3=0.f;
        if (node < N_NODES) {
            const float* xp = x + (size_t)node * IN_C + o * 8;
            if (o < 20) {                      // k0+7 <= 159+7 < 165: unmasked
                float4 va, vb;
                __builtin_memcpy(&va, xp, 16);       // 4B-aligned vector load
                __builtin_memcpy(&vb, xp + 4, 16);
                va0=va.x; va1=va.y; va2=va.z; va3=va.w;
                vb0=vb.x; vb1=vb.y; vb2=vb.z; vb3=vb.w;
            } else if (o == 20) {              // k 160..167; valid 160..164
                float4 va;
                __builtin_memcpy(&va, xp, 16);
                va0=va.x; va1=va.y; va2=va.z; va3=va.w;
                vb0 = xp[4];
            }                                   // o == 21: all zero pad
        }
        unsigned u[8] = {__float_as_uint(va0), __float_as_uint(va1),
                         __float_as_uint(va2), __float_as_uint(va3),
                         __float_as_uint(vb0), __float_as_uint(vb1),
                         __float_as_uint(vb2), __float_as_uint(vb3)};
        unsigned ph[4], pl[4];
        #pragma unroll
        for (int q = 0; q < 4; ++q) {
            unsigned ue = u[2*q], uo = u[2*q+1];
            ph[q] = (ue >> 16) | (uo & 0xFFFF0000u);     // trunc high halves
            float re = __uint_as_float(ue) - __uint_as_float(ue & 0xFFFF0000u);
            float ro = __uint_as_float(uo) - __uint_as_float(uo & 0xFFFF0000u);
            pl[q] = (__float_as_uint(re) >> 16) |
                    (__float_as_uint(ro) & 0xFFFF0000u); // trunc residuals
        }
        unsigned short* base = asr + s * 1024 + (kg * 32 + row) * 8;
        *(uint4*)(base)       = make_uint4(ph[0], ph[1], ph[2], ph[3]);
        *(uint4*)(base + 512) = make_uint4(pl[0], pl[1], pl[2], pl[3]);
    }
    __syncthreads();

    f32x16 acc0, acc1, accA;
    #pragma unroll
    for (int r = 0; r < 16; ++r) { acc0[r] = 0.f; acc1[r] = 0.f; accA[r] = 0.f; }
    const int ns0 = 2 * w, ns1 = 2 * w + 1;
    const int afo = (half * 32 + ln) * 8;     // A/Wa frag offset (shorts)
    const int fo0 = ((ns0 * 2 + half) * 32 + ln) * 8;
    const int fo1 = ((ns1 * 2 + half) * 32 + ln) * 8;
    for (int s = 0; s < NSTEP; ++s) {
        const unsigned short* ab = asr + s * 1024;
        s16x8 a_h = *(const s16x8*)(ab + afo);
        s16x8 a_l = *(const s16x8*)(ab + 512 + afo);
        const unsigned short* bb = bImg + (size_t)s * 8192;
        s16x8 bh0 = *(const s16x8*)(bb + fo0);
        s16x8 bh1 = *(const s16x8*)(bb + fo1);
        s16x8 bl0 = *(const s16x8*)(bb + 4096 + fo0);
        s16x8 bl1 = *(const s16x8*)(bb + 4096 + fo1);
        acc0 = __builtin_amdgcn_mfma_f32_32x32x16_bf16(a_h, bh0, acc0, 0, 0, 0);
        acc1 = __builtin_amdgcn_mfma_f32_32x32x16_bf16(a_h, bh1, acc1, 0, 0, 0);
        acc0 = __builtin_amdgcn_mfma_f32_32x32x16_bf16(a_h, bl0, acc0, 0, 0, 0);
        acc1 = __builtin_amdgcn_mfma_f32_32x32x16_bf16(a_h, bl1, acc1, 0, 0, 0);
        acc0 = __builtin_amdgcn_mfma_f32_32x32x16_bf16(a_l, bh0, acc0, 0, 0, 0);
        acc1 = __builtin_amdgcn_mfma_f32_32x32x16_bf16(a_l, bh1, acc1, 0, 0, 0);
        if (w == 0) {                          // wave-uniform branch
            const unsigned short* wb = waImg + (size_t)s * 1024;
            s16x8 wah = *(const s16x8*)(wb + afo);
            s16x8 wal = *(const s16x8*)(wb + 512 + afo);
            accA = __builtin_amdgcn_mfma_f32_32x32x16_bf16(a_h, wah, accA, 0, 0, 0);
            accA = __builtin_amdgcn_mfma_f32_32x32x16_bf16(a_h, wal, accA, 0, 0, 0);
            accA = __builtin_amdgcn_mfma_f32_32x32x16_bf16(a_l, wah, accA, 0, 0, 0);
        }
    }
    #pragma unroll
    for (int t = 0; t < 2; ++t) {
        const int colg = w * 64 + t * 32 + ln;
        #pragma unroll
        for (int r = 0; r < 16; ++r) {
            int row = (r & 3) + 8 * (r >> 2) + 4 * half;
            int gr = row0 + row;
            if (gr < N_NODES) {
                float a = t ? acc1[r] : acc0[r];
                h[(size_t)gr * HID + colg] = f32_bf16(a);
            }
        }
    }
    if (w == 0 && ln < 16) {
        int head = ln >> 1;
        float* ap = (ln & 1) ? a_dst : a_src;
        #pragma unroll
        for (int r = 0; r < 16; ++r) {
            int row = (r & 3) + 8 * (r >> 2) + 4 * half;
            int gr = row0 + row;
            if (gr < N_NODES) ap[gr * 8 + head] = accA[r] * LOG2E;
        }
    }
}

// ============ fused: MFMA gemm || partition-filtered slotted scatter ========
// Self-loops NOT inserted (added analytically in agg1/agg2).
__global__ __launch_bounds__(256) void fusedAB_kernel(
        const float* __restrict__ x,
        const unsigned short* __restrict__ bImg,
        const unsigned short* __restrict__ waImg,
        unsigned short* __restrict__ h, float* __restrict__ a_src,
        float* __restrict__ a_dst,
        const int* __restrict__ src, const int* __restrict__ dst,
        int* __restrict__ deg, unsigned short* __restrict__ csr) {
    __shared__ unsigned short asr[NSTEP * 1024];   // 22.5 KB A-fragment region
    if (blockIdx.x < GEMM_BLOCKS) {
        gemm_mfma_block(blockIdx.x, x, bImg, waImg, h, a_src, a_dst, asr);
    } else {
        const int sb  = blockIdx.x - GEMM_BLOCKS;   // 0..SCB-1
        const int cls = sb & 7;
        const int blk = sb >> 3;                    // 0..255 within class
        const int lo = cls * NPP;
        const int hi = (lo + NPP < N_NODES) ? lo + NPP : N_NODES;
        const int t = blk * 256 + threadIdx.x;      // 0..65535 within class
        const int4* dst4 = (const int4*)dst;        // int4 scan of real edges
        for (int uu = t; uu < NE4; uu += SGRP * 256) {
            int4 dv = dst4[uu];
            #pragma unroll
            for (int j = 0; j < 4; ++j) {
                int d = (j == 0) ? dv.x : (j == 1) ? dv.y : (j == 2) ? dv.z : dv.w;
                if (d >= lo && d < hi) {
                    int slot = atomicAdd(&deg[d], 1);
                    csr[(size_t)d * CAPL + slot] = (unsigned short)src[4 * uu + j];
                }
            }
        }
    }
}

// ============ Layer 1 fused: softmax-aggregate(bf16 gather) + bias + ELU
//              + layer-2 GEMM.  Register-resident edge list, 32-edge rounds,
//              analytic self-loop. (R10 — pinned at the 422MB/3.6TB/s IC
//              floor; three instruction-structure variants all ~118-122us,
//              three head-split locality variants all worse. FLOOR.) ========
__global__ __launch_bounds__(256) void agg1_fused_kernel(
        const int* __restrict__ deg, const unsigned short* __restrict__ csr,
        const float* __restrict__ a_src, const float* __restrict__ a_dst,
        const unsigned short* __restrict__ h1, const float* __restrict__ bias1,
        const float* __restrict__ W2,
        const float* __restrict__ as2, const float* __restrict__ ad2,
        float4* __restrict__ pk, float* __restrict__ a2d) {
    int wid = (blockIdx.x * 256 + threadIdx.x) >> 6;
    int l = threadIdx.x & 63;
    if (wid >= N_NODES) return;
    const int el = l >> 5;                    // edge parity (half-wave)
    const int q  = l & 31;                    // channel octet id
    const int hd = q >> 2;                    // head
    const int ch = q * 8;                     // ushort offset (16 B per lane)
    const int sh = el * 16;                   // halfword select shift
    const uint4* lst4 = (const uint4*)(csr + (size_t)wid * CAPL);
    const int n = deg[wid];
    const float ad_p = a_dst[wid * 8 + hd];
    float den = 0.f;
    f32x2 ac0 = {0.f, 0.f}, ac1 = {0.f, 0.f}, ac2 = {0.f, 0.f}, ac3 = {0.f, 0.f};

    uint4 ca = lst4[0], cb = lst4[1], cc = lst4[2], cd = lst4[3];
    int i = 0;

#define EXTRACT_S(S_, MK_, OFF_, W0_, W1_, W2_, W3_, W4_, W5_, W6_, W7_)      \
    {                                                                          \
        unsigned wsel_[8] = {W0_, W1_, W2_, W3_, W4_, W5_, W6_, W7_};          \
        _Pragma("unroll")                                                      \
        for (int j = 0; j < 8; ++j) {                                          \
            int sv = (int)((wsel_[j] >> sh) & 0xFFFFu);                        \
            int e = i + OFF_ + 2 * j + el;                                     \
            bool ok = e < n;                                                   \
            MK_[j] = ok ? 1.f : 0.f;                                           \
            S_[j] = ok ? sv : wid;                                             \
        }                                                                      \
    }

#define GATHER_ACC(S_, MK_, CNT_)                                              \
    {                                                                          \
        uint4 v_[CNT_];                                                        \
        _Pragma("unroll")                                                      \
        for (int j = 0; j < CNT_; ++j)                                         \
            v_[j] = *(const uint4*)(h1 + (size_t)S_[j] * HID + ch);            \
        float w_[CNT_];                                                        \
        _Pragma("unroll")                                                      \
        for (int j = 0; j < CNT_; ++j)                                         \
            w_[j] = MK_[j] * e2l(a_src[S_[j] * 8 + hd] + ad_p);                \
        _Pragma("unroll")                                                      \
        for (int j = 0; j < CNT_; ++j) {                                       \
            den += w_[j];                                                      \
            f32x2 w2_ = {w_[j], w_[j]};                                        \
            ac0 += w2_ * (f32x2){bflo(v_[j].x), bfhi(v_[j].x)};                \
            ac1 += w2_ * (f32x2){bflo(v_[j].y), bfhi(v_[j].y)};                \
            ac2 += w2_ * (f32x2){bflo(v_[j].z), bfhi(v_[j].z)};                \
            ac3 += w2_ * (f32x2){bflo(v_[j].w), bfhi(v_[j].w)};                \
        }                                                                      \
    }

    for (; i + 32 <= n; i += 32) {
        uint4 na = ca, nb = cb, nc = cc, nd = cd;
        if (i + 32 < n) {
            na = lst4[(i >> 3) + 4]; nb = lst4[(i >> 3) + 5];
            nc = lst4[(i >> 3) + 6]; nd = lst4[(i >> 3) + 7];
        }
        int s[16]; float mk[16];
        EXTRACT_S(s, mk, 0,  ca.x, ca.y, ca.z, ca.w, cb.x, cb.y, cb.z, cb.w)
        EXTRACT_S((s + 8), (mk + 8), 16, cc.x, cc.y, cc.z, cc.w, cd.x, cd.y, cd.z, cd.w)
        GATHER_ACC(s, mk, 16)
        ca = na; cb = nb; cc = nc; cd = nd;
    }
    if (i + 16 <= n) {
        int s[8]; float mk[8];
        EXTRACT_S(s, mk, 0, ca.x, ca.y, ca.z, ca.w, cb.x, cb.y, cb.z, cb.w)
        GATHER_ACC(s, mk, 8)
        ca = cc; cb = cd;
        i += 16;
    }
    if (i < n) {
        int s[8]; float mk[8];
        EXTRACT_S(s, mk, 0, ca.x, ca.y, ca.z, ca.w, cb.x, cb.y, cb.z, cb.w)
        GATHER_ACC(s, mk, 8)
    }
#undef EXTRACT_S
#undef GATHER_ACC

    float accs[8] = {ac0.x, ac0.y, ac1.x, ac1.y, ac2.x, ac2.y, ac3.x, ac3.y};
    den += __shfl_xor(den, 32);
    #pragma unroll
    for (int k = 0; k < 8; ++k) accs[k] += __shfl_xor(accs[k], 32);

    // ---- explicit self-loop term (not in csr) ----
    {
        float wsf = e2l(a_src[wid * 8 + hd] + ad_p);
        uint4 v = *(const uint4*)(h1 + (size_t)wid * HID + ch);
        den += wsf;
        accs[0] += wsf * bflo(v.x); accs[1] += wsf * bfhi(v.x);
        accs[2] += wsf * bflo(v.y); accs[3] += wsf * bfhi(v.y);
        accs[4] += wsf * bflo(v.z); accs[5] += wsf * bfhi(v.z);
        accs[6] += wsf * bflo(v.w); accs[7] += wsf * bfhi(v.w);
    }

    const float inv = 1.f / den;
    float4 bva = *(const float4*)(bias1 + ch);
    float4 bvb = *(const float4*)(bias1 + ch + 4);
    float o[8];
    o[0] = accs[0] * inv + bva.x; o[1] = accs[1] * inv + bva.y;
    o[2] = accs[2] * inv + bva.z; o[3] = accs[3] * inv + bva.w;
    o[4] = accs[4] * inv + bvb.x; o[5] = accs[5] * inv + bvb.y;
    o[6] = accs[6] * inv + bvb.z; o[7] = accs[7] * inv + bvb.w;
    #pragma unroll
    for (int k = 0; k < 8; ++k)               // ELU; exp-1 abs err ~1e-7 << tol
        o[k] = o[k] > 0.f ? o[k] : (__expf(o[k]) - 1.f);
    const float* wv = W2 + q * 16;
    float4 w0 = *(const float4*)(wv);
    float4 w1 = *(const float4*)(wv + 4);
    float4 w2 = *(const float4*)(wv + 8);
    float4 w3 = *(const float4*)(wv + 12);
    float p0 = o[0]*w0.x + o[1]*w0.z + o[2]*w1.x + o[3]*w1.z
             + o[4]*w2.x + o[5]*w2.z + o[6]*w3.x + o[7]*w3.z;
    float p1 = o[0]*w0.y + o[1]*w0.w + o[2]*w1.y + o[3]*w1.w
             + o[4]*w2.y + o[5]*w2.w + o[6]*w3.y + o[7]*w3.w;
    #pragma unroll
    for (int off = 16; off; off >>= 1) {
        p0 += __shfl_xor(p0, off);
        p1 += __shfl_xor(p1, off);
    }
    if (l == 0) {
        pk[wid] = make_float4(p0, p1, (p0 * as2[0] + p1 * as2[1]) * LOG2E, 0.f);
        a2d[wid] = (p0 * ad2[0] + p1 * ad2[1]) * LOG2E;
    }
}

// ============ Layer 2 fused: 16 lanes per node, 2-deep rounds.
// Masked slots clamp to `node` (uniform, cache-hit). Self term at l==0. ====
__global__ __launch_bounds__(256) void agg2_fused_kernel(
        const int* __restrict__ deg, const unsigned short* __restrict__ csr,
        const float4* __restrict__ pk, const float* __restrict__ a2d,
        const float* __restrict__ b2, float* __restrict__ out) {
    int t = blockIdx.x * 256 + threadIdx.x;
    int node = t >> 4;
    int l = t & 15;
    if (node >= N_NODES) return;
    const unsigned short* lst = csr + (size_t)node * CAPL;
    const int n = deg[node];
    const float adv = a2d[node];
    float sm = 0.f, acc0 = 0.f, acc1 = 0.f;
    for (int i = l; i < n; i += 32) {
        int s0 = lst[i];
        int e1 = i + 16;
        bool ok1 = e1 < n;
        float m1 = ok1 ? 1.f : 0.f;
        int s1 = ok1 ? lst[e1] : node;
        float4 p0 = pk[s0], p1 = pk[s1];
        float w0 = e2l(p0.z + adv);
        float w1 = m1 * e2l(p1.z + adv);
        sm += w0 + w1;
        acc0 += w0 * p0.x + w1 * p1.x;
        acc1 += w0 * p0.y + w1 * p1.y;
    }
    #pragma unroll
    for (int off = 8; off; off >>= 1) {       // xor stays within the 16-group
        sm   += __shfl_xor(sm, off);
        acc0 += __shfl_xor(acc0, off);
        acc1 += __shfl_xor(acc1, off);
    }
    if (l == 0) {
        float4 ps = pk[node];                 // explicit self-loop term
        float wsf = e2l(ps.z + adv);
        sm += wsf;
        acc0 += wsf * ps.x;
        acc1 += wsf * ps.y;
        *(float2*)(out + node * 2) =
            make_float2(acc0 / sm + b2[0], acc1 / sm + b2[1]);
    }
}

extern "C" void kernel_launch(void* const* d_in, const int* in_sizes, int n_in,
                              void* d_out, int out_size, void* d_ws, size_t ws_size,
                              hipStream_t stream) {
    (void)in_sizes; (void)n_in; (void)out_size; (void)ws_size;
    const float* x        = (const float*)d_in[0];
    const int*   ei       = (const int*)d_in[1];
    const float* W1       = (const float*)d_in[2];
    const float* att_src1 = (const float*)d_in[3];
    const float* att_dst1 = (const float*)d_in[4];
    const float* b1       = (const float*)d_in[5];
    const float* W2       = (const float*)d_in[6];
    const float* att_src2 = (const float*)d_in[7];
    const float* att_dst2 = (const float*)d_in[8];
    const float* b2       = (const float*)d_in[9];
    float* out = (float*)d_out;

    const int* src = ei;
    const int* dst = ei + N_EDGES;

    // ---- workspace carve-up (bytes); total ~39.8 MB ----
    char* ws = (char*)d_ws;
    size_t off = 0;
    unsigned short* h1 = (unsigned short*)(ws + off);
    off += (size_t)N_NODES * HID * 2;                                      // 25.6 MB
    float* a_src1 = (float*)(ws + off); off += (size_t)N_NODES * HEADS * 4;
    float* a_dst1 = (float*)(ws + off); off += (size_t)N_NODES * HEADS * 4;
    float4* pk = (float4*)(ws + off); off += (size_t)N_NODES * 16;
    float* a2d = (float*)(ws + off); off += (size_t)N_NODES * 4;
    int* deg    = (int*)(ws + off); off += (size_t)N_NODES * 4;
    unsigned short* csr = (unsigned short*)(ws + off);
    off += (size_t)N_NODES * CAPL * 2;                                     // 9.6 MB
    unsigned short* bImg  = (unsigned short*)(ws + off); off += BIMG_BYTES;  // 176 KB
    unsigned short* waImg = (unsigned short*)(ws + off); off += WAIMG_BYTES; // 22.5 KB

    hipMemsetAsync(deg, 0, (size_t)N_NODES * 4, stream);

    const int NW = (N_NODES * 64 + 255) / 256;

    // ---- prepass: W and Wa fragment-major split-bf16 images ----
    prep_kernel<<<WPB + WAB, 256, 0, stream>>>(W1, att_src1, att_dst1, bImg, waImg);

    // ---- MFMA gemm + att dots || scatter (no self-loops) ----
    fusedAB_kernel<<<GEMM_BLOCKS + SCB, 256, 0, stream>>>(
        x, bImg, waImg, h1, a_src1, a_dst1, src, dst, deg, csr);

    // ---- layer 1 aggregate + ELU + layer 2 GEMM (fused) ----
    agg1_fused_kernel<<<NW, 256, 0, stream>>>(
        deg, csr, a_src1, a_dst1, h1, b1, W2, att_src2, att_dst2, pk, a2d);

    // ---- layer 2 aggregate ----
    agg2_fused_kernel<<<(N_NODES * 16 + 255) / 256, 256, 0, stream>>>(
        deg, csr, pk, a2d, b2, out);
}